// Round 1
// baseline (1600.300 us; speedup 1.0000x reference)
//
#include <hip/hip_runtime.h>

typedef __bf16 bf16;
typedef __bf16 bf16x8 __attribute__((ext_vector_type(8)));
typedef float  f32x4  __attribute__((ext_vector_type(4)));

#define MFMA16(a, b, c) __builtin_amdgcn_mfma_f32_16x16x32_bf16((a), (b), (c), 0, 0, 0)

constexpr int kDM = 1024;   // model dim; K proj = N proj = 1024

static __device__ inline f32x4 zero4() { f32x4 z = {0.f, 0.f, 0.f, 0.f}; return z; }

// ---------------------------------------------------------------------------
// GEMM: out_bf16[M][1024] = X_fp32[M][1024] @ W_fp32[1024][1024] + bias
// Block: 256 thr (4 waves), tile 64(M) x 128(N), BK=64. Waves 2x2, each 32x64.
// MFMA 16x16x32 bf16. A-frag: A[m=l16][k=quad*8+j]; B-frag: B[k=quad*8+j][n=l16];
// D: [row=quad*4+r][col=l16]  (HW-verified layouts).
// ---------------------------------------------------------------------------
__global__ __launch_bounds__(256) void gemm_proj(
    const float* __restrict__ X, const float* __restrict__ W,
    const float* __restrict__ bias, bf16* __restrict__ out)
{
    __shared__ bf16 As[64][72];    // [m][k], stride 144B (16B-aligned, bank-friendly)
    __shared__ bf16 Bs[128][72];   // W transposed: [n][k]

    const int tid  = threadIdx.x;
    const int m0   = blockIdx.x * 64;
    const int n0   = blockIdx.y * 128;
    const int wave = tid >> 6;
    const int lane = tid & 63;
    const int quad = lane >> 4;
    const int l16  = lane & 15;
    const int mb   = (wave & 1) * 32;
    const int nb   = (wave >> 1) * 64;

    f32x4 acc[2][4];
    #pragma unroll
    for (int i = 0; i < 2; i++)
        #pragma unroll
        for (int j = 0; j < 4; j++) acc[i][j] = zero4();

    for (int k0 = 0; k0 < kDM; k0 += 64) {
        __syncthreads();
        // stage A: 64 rows x 64 k fp32 -> bf16 (1024 float4, 4/thread, coalesced)
        #pragma unroll
        for (int i = 0; i < 4; i++) {
            int idx = tid + 256 * i;
            int row = idx >> 4, kq = idx & 15;
            float4 v = *(const float4*)&X[(size_t)(m0 + row) * kDM + k0 + kq * 4];
            bf16* dst = &As[row][kq * 4];
            dst[0] = (bf16)v.x; dst[1] = (bf16)v.y; dst[2] = (bf16)v.z; dst[3] = (bf16)v.w;
        }
        // stage W transposed: 64 k-rows x 128 n (2048 float4, 8/thread, coalesced reads)
        #pragma unroll
        for (int i = 0; i < 8; i++) {
            int idx = tid + 256 * i;
            int kk = idx >> 5, nq = idx & 31;
            float4 v = *(const float4*)&W[(size_t)(k0 + kk) * kDM + n0 + nq * 4];
            Bs[nq * 4 + 0][kk] = (bf16)v.x;
            Bs[nq * 4 + 1][kk] = (bf16)v.y;
            Bs[nq * 4 + 2][kk] = (bf16)v.z;
            Bs[nq * 4 + 3][kk] = (bf16)v.w;
        }
        __syncthreads();
        #pragma unroll
        for (int ks = 0; ks < 2; ks++) {
            bf16x8 a[2], b[4];
            #pragma unroll
            for (int i = 0; i < 2; i++)
                a[i] = *(const bf16x8*)&As[mb + i * 16 + l16][ks * 32 + quad * 8];
            #pragma unroll
            for (int j = 0; j < 4; j++)
                b[j] = *(const bf16x8*)&Bs[nb + j * 16 + l16][ks * 32 + quad * 8];
            #pragma unroll
            for (int i = 0; i < 2; i++)
                #pragma unroll
                for (int j = 0; j < 4; j++)
                    acc[i][j] = MFMA16(a[i], b[j], acc[i][j]);
        }
    }
    #pragma unroll
    for (int i = 0; i < 2; i++)
        #pragma unroll
        for (int j = 0; j < 4; j++) {
            const int n = n0 + nb + j * 16 + l16;
            const float bv = bias[n];
            #pragma unroll
            for (int r = 0; r < 4; r++) {
                const int m = m0 + mb + i * 16 + quad * 4 + r;
                out[(size_t)m * kDM + n] = (bf16)(acc[i][j][r] + bv);
            }
        }
}

// ---------------------------------------------------------------------------
// In-place multimodal 3D RoPE on bf16 [N][NH*HD] buffer.
// Thread handles the (d, d+64) pair within one head -> no write race.
// angle = p * 10000^(-d/64); axis: d<16 -> t, d<40 -> h, else -> w (d in [0,64)).
// slow (query): n = t*256+i*16+j, p=( floor(31t/7), 2i+1, 2j+1 )
// fast (key):   n = t*1024+i*32+j, p=( t, i, j )
// ---------------------------------------------------------------------------
__global__ __launch_bounds__(256) void rope_kernel(bf16* __restrict__ buf, int fast)
{
    const int gid = blockIdx.x * 256 + threadIdx.x;
    const int d = gid & 63;
    const int h = (gid >> 6) & 7;
    const int n = gid >> 9;
    int pt, ph, pw;
    if (fast) { pt = n >> 10; ph = (n >> 5) & 31; pw = n & 31; }
    else      { int tq = n >> 8; pt = (31 * tq) / 7; ph = 2 * ((n >> 4) & 15) + 1; pw = 2 * (n & 15) + 1; }
    const int p = (d < 16) ? pt : ((d < 40) ? ph : pw);
    // 0.20762050593045951 = log2(10000)/64
    const float angle = (float)p * exp2f((float)d * -0.20762050593045951f);
    const float c = cosf(angle), s = sinf(angle);
    const size_t i1 = (size_t)n * kDM + h * 128 + d;
    const float x1 = (float)buf[i1], x2 = (float)buf[i1 + 64];
    buf[i1]      = (bf16)(x1 * c - x2 * s);
    buf[i1 + 64] = (bf16)(x2 * c + x1 * s);
}

// ---------------------------------------------------------------------------
// Flash attention. Block = (qb 0..3, h 0..7, t 0..7), 256 thr = 4 waves.
// Wave w owns 16 q-rows (qb*64 + w*16 ..). Iterate 128 key-tiles of 32.
// S = Q Kt (both row-major [row][d] -> A/B frags identical pattern).
// Online softmax per q-row via quad-local shfl_xor reductions.
// P: C-layout -> (LDS) -> A-layout; V transposed in LDS for PV B-frags.
// ---------------------------------------------------------------------------
__global__ __launch_bounds__(256) void attn_kernel(
    const bf16* __restrict__ qh, const bf16* __restrict__ kh,
    const bf16* __restrict__ vh, float* __restrict__ out)
{
    __shared__ bf16 Ks[32][136];      // [key][d], stride 272B (16B-aligned)
    __shared__ bf16 Vt[128][40];      // [d][key], stride 80B
    __shared__ bf16 Ps[4][16][40];    // per-wave P round-trip [q][key]

    const int tid  = threadIdx.x;
    const int qb   = blockIdx.x, h = blockIdx.y, t = blockIdx.z;
    const int wave = tid >> 6;
    const int lane = tid & 63;
    const int quad = lane >> 4, l16 = lane & 15;

    // Q fragments (held in registers the whole kernel)
    const int qrow = qb * 64 + wave * 16 + l16;
    const size_t qbase = ((size_t)(t * 256 + qrow)) * kDM + h * 128;
    bf16x8 aq[4];
    #pragma unroll
    for (int kb = 0; kb < 4; kb++)
        aq[kb] = *(const bf16x8*)&qh[qbase + kb * 32 + quad * 8];

    f32x4 o[8];
    #pragma unroll
    for (int j = 0; j < 8; j++) o[j] = zero4();
    float m_run[4], l_run[4];
    #pragma unroll
    for (int r = 0; r < 4; r++) { m_run[r] = -1e30f; l_run[r] = 0.f; }
    const float scale = 0.08838834764831845f;   // 1/sqrt(128)

    // V staging assignment: lanes vary in key-row (not d) to avoid the
    // all-lanes-same-bank transpose-write pattern.
    const int v_row = tid & 31, v_c0 = tid >> 5;

    for (int kt = 0; kt < 128; kt++) {
        const int kbase = t * 4096 + kt * 32;
        __syncthreads();
        // K tile row-major (coalesced 256B rows)
        #pragma unroll
        for (int i = 0; i < 2; i++) {
            int idx = tid + 256 * i;
            int row = idx >> 4, c = idx & 15;
            *(uint4*)&Ks[row][c * 8] =
                *(const uint4*)&kh[((size_t)(kbase + row)) * kDM + h * 128 + c * 8];
        }
        // V tile transposed
        #pragma unroll
        for (int i = 0; i < 2; i++) {
            int c = v_c0 + 8 * i;
            uint4 vv = *(const uint4*)&vh[((size_t)(kbase + v_row)) * kDM + h * 128 + c * 8];
            const bf16* vp = (const bf16*)&vv;
            #pragma unroll
            for (int j = 0; j < 8; j++) Vt[c * 8 + j][v_row] = vp[j];
        }
        __syncthreads();

        // S = Q K^T   (16 q x 32 keys per wave)
        f32x4 s[2];
        s[0] = zero4(); s[1] = zero4();
        #pragma unroll
        for (int kb = 0; kb < 4; kb++) {
            bf16x8 b0 = *(const bf16x8*)&Ks[l16][kb * 32 + quad * 8];
            bf16x8 b1 = *(const bf16x8*)&Ks[16 + l16][kb * 32 + quad * 8];
            s[0] = MFMA16(aq[kb], b0, s[0]);
            s[1] = MFMA16(aq[kb], b1, s[1]);
        }

        // online softmax; row r of this quad = q (quad*4+r), cols spread over 16 lanes
        float alpha[4], p0[4], p1[4];
        #pragma unroll
        for (int r = 0; r < 4; r++) {
            float sv0 = s[0][r] * scale, sv1 = s[1][r] * scale;
            float mx = fmaxf(sv0, sv1);
            #pragma unroll
            for (int off = 1; off < 16; off <<= 1) mx = fmaxf(mx, __shfl_xor(mx, off));
            float mn = fmaxf(m_run[r], mx);
            float a  = __expf(m_run[r] - mn);
            p0[r] = __expf(sv0 - mn);
            p1[r] = __expf(sv1 - mn);
            float ls = p0[r] + p1[r];
            #pragma unroll
            for (int off = 1; off < 16; off <<= 1) ls += __shfl_xor(ls, off);
            m_run[r] = mn;
            l_run[r] = l_run[r] * a + ls;
            alpha[r] = a;
        }
        // P: C-layout -> LDS (bf16) -> A-layout (wave-local round trip)
        #pragma unroll
        for (int r = 0; r < 4; r++) {
            Ps[wave][quad * 4 + r][l16]      = (bf16)p0[r];
            Ps[wave][quad * 4 + r][16 + l16] = (bf16)p1[r];
        }
        #pragma unroll
        for (int j = 0; j < 8; j++)
            #pragma unroll
            for (int r = 0; r < 4; r++) o[j][r] *= alpha[r];
        bf16x8 pa = *(const bf16x8*)&Ps[wave][l16][quad * 8];
        // O += P V  (8 d-tiles of 16)
        #pragma unroll
        for (int j = 0; j < 8; j++) {
            bf16x8 bv = *(const bf16x8*)&Vt[j * 16 + l16][quad * 8];
            o[j] = MFMA16(pa, bv, o[j]);
        }
    }

    // epilogue: normalize and write out[t][s][h*128+d] fp32
    #pragma unroll
    for (int r = 0; r < 4; r++) {
        const float inv_l = 1.0f / l_run[r];
        const int srow = qb * 64 + wave * 16 + quad * 4 + r;
        const size_t obase = ((size_t)(t * 256 + srow)) * kDM + h * 128;
        #pragma unroll
        for (int j = 0; j < 8; j++)
            out[obase + j * 16 + l16] = o[j][r] * inv_l;
    }
}

// ---------------------------------------------------------------------------
extern "C" void kernel_launch(void* const* d_in, const int* in_sizes, int n_in,
                              void* d_out, int out_size, void* d_ws, size_t ws_size,
                              hipStream_t stream)
{
    const float* q  = (const float*)d_in[0];
    const float* k  = (const float*)d_in[1];
    const float* v  = (const float*)d_in[2];
    const float* Wq = (const float*)d_in[3];
    const float* bq = (const float*)d_in[4];
    const float* Wk = (const float*)d_in[5];
    const float* bk = (const float*)d_in[6];
    const float* Wv = (const float*)d_in[7];
    const float* bv = (const float*)d_in[8];
    float* out = (float*)d_out;

    // workspace: bf16 qh (4MB) | kh (64MB) | vh (64MB)
    bf16* qh = (bf16*)d_ws;
    bf16* kh = qh + (size_t)2048 * 1024;
    bf16* vh = kh + (size_t)32768 * 1024;

    gemm_proj<<<dim3(32, 8),  dim3(256), 0, stream>>>(q, Wq, bq, qh);
    gemm_proj<<<dim3(512, 8), dim3(256), 0, stream>>>(k, Wk, bk, kh);
    gemm_proj<<<dim3(512, 8), dim3(256), 0, stream>>>(v, Wv, bv, vh);
    rope_kernel<<<(2048 * 512) / 256,  dim3(256), 0, stream>>>(qh, 0);
    rope_kernel<<<(32768 * 512) / 256, dim3(256), 0, stream>>>(kh, 1);
    attn_kernel<<<dim3(4, 8, 8), dim3(256), 0, stream>>>(qh, kh, vh, out);
}

// Round 2
// 902.325 us; speedup vs baseline: 1.7735x; 1.7735x over previous
//
#include <hip/hip_runtime.h>

typedef __bf16 bf16;
typedef __bf16 bf16x8 __attribute__((ext_vector_type(8)));
typedef float  f32x4  __attribute__((ext_vector_type(4)));

#define MFMA16(a, b, c) __builtin_amdgcn_mfma_f32_16x16x32_bf16((a), (b), (c), 0, 0, 0)

// async global->LDS, 16B per lane; LDS dest = wave-uniform base + lane*16
#define GLOAD_LDS16(gptr, lptr)                                              \
    __builtin_amdgcn_global_load_lds(                                        \
        (const __attribute__((address_space(1))) unsigned int*)(gptr),       \
        (__attribute__((address_space(3))) unsigned int*)(lptr), 16, 0, 0)

constexpr int kDM = 1024;

static __device__ inline f32x4 zero4() { f32x4 z = {0.f, 0.f, 0.f, 0.f}; return z; }

// ---------------------------------------------------------------------------
// W fp32 [k][n] -> Wt bf16 [n][k]  (64x64 LDS-tiled transpose+convert)
// ---------------------------------------------------------------------------
__global__ __launch_bounds__(256) void transpose_w(
    const float* __restrict__ W, bf16* __restrict__ Wt)
{
    __shared__ bf16 T[64][68];   // stride 136B (8B-aligned for ushort4)
    const int tid = threadIdx.x;
    const int n0 = blockIdx.x * 64, k0 = blockIdx.y * 64;
    #pragma unroll
    for (int i = 0; i < 4; i++) {
        const int kk = (tid >> 4) + i * 16, nn4 = (tid & 15) * 4;
        float4 v = *(const float4*)&W[(size_t)(k0 + kk) * kDM + n0 + nn4];
        T[nn4 + 0][kk] = (bf16)v.x; T[nn4 + 1][kk] = (bf16)v.y;
        T[nn4 + 2][kk] = (bf16)v.z; T[nn4 + 3][kk] = (bf16)v.w;
    }
    __syncthreads();
    #pragma unroll
    for (int i = 0; i < 4; i++) {
        const int nn = (tid >> 4) + i * 16, kc = (tid & 15) * 4;
        *(ushort4*)&Wt[(size_t)(n0 + nn) * kDM + k0 + kc] = *(const ushort4*)&T[nn][kc];
    }
}

// ---------------------------------------------------------------------------
// GEMM (m97 structure): out_bf16[M][1024] = X_fp32[M][1024] @ Wt_bf16[N][K]^T + bias
// 128x128 tile, BK=64, 4 waves 2x2 (each 64x64 = 4x4 MFMA tiles).
// A staged as fp32 via global_load_lds (32KB), converted bf16 on frag read.
// B staged as bf16 via global_load_lds (16KB), row-contiguous (no transpose).
// grid.x = n-block (8) so consecutive blocks share X rows (L2-friendly).
// ---------------------------------------------------------------------------
__global__ __launch_bounds__(256) void gemm_bt(
    const float* __restrict__ X, const bf16* __restrict__ Wt,
    const float* __restrict__ bias, bf16* __restrict__ out)
{
    __shared__ float Asf[128 * 64];  // [m][k] fp32, row 256B
    __shared__ bf16  Bsb[128 * 64];  // [n][k] bf16, row 128B

    const int tid  = threadIdx.x;
    const int n0   = blockIdx.x * 128;
    const int m0   = blockIdx.y * 128;
    const int wave = tid >> 6;
    const int lane = tid & 63;
    const int quad = lane >> 4, l16 = lane & 15;
    const int mb   = (wave & 1) * 64, nb = (wave >> 1) * 64;

    f32x4 acc[4][4];
    #pragma unroll
    for (int i = 0; i < 4; i++)
        #pragma unroll
        for (int j = 0; j < 4; j++) acc[i][j] = zero4();

    for (int k0 = 0; k0 < kDM; k0 += 64) {
        __syncthreads();
        // A: 32 chunks of 1KB (4 fp32 rows each); 8 per wave
        #pragma unroll
        for (int i = 0; i < 8; i++) {
            const int c = wave * 8 + i;
            GLOAD_LDS16(&X[(size_t)(m0 + c * 4 + (lane >> 4)) * kDM + k0 + (lane & 15) * 4],
                        &Asf[c * 256]);
        }
        // B: 16 chunks of 1KB (8 bf16 rows each); 4 per wave
        #pragma unroll
        for (int i = 0; i < 4; i++) {
            const int c = wave * 4 + i;
            GLOAD_LDS16(&Wt[(size_t)(n0 + c * 8 + (lane >> 3)) * kDM + k0 + (lane & 7) * 8],
                        &Bsb[c * 512]);
        }
        __syncthreads();
        #pragma unroll
        for (int ks = 0; ks < 2; ks++) {
            bf16x8 a[4], b[4];
            #pragma unroll
            for (int i = 0; i < 4; i++) {
                const float* p = &Asf[(mb + i * 16 + l16) * 64 + ks * 32 + quad * 8];
                f32x4 u0 = *(const f32x4*)p;
                f32x4 u1 = *(const f32x4*)(p + 4);
                #pragma unroll
                for (int e = 0; e < 4; e++) { a[i][e] = (bf16)u0[e]; a[i][4 + e] = (bf16)u1[e]; }
            }
            #pragma unroll
            for (int j = 0; j < 4; j++)
                b[j] = *(const bf16x8*)&Bsb[(nb + j * 16 + l16) * 64 + ks * 32 + quad * 8];
            #pragma unroll
            for (int i = 0; i < 4; i++)
                #pragma unroll
                for (int j = 0; j < 4; j++)
                    acc[i][j] = MFMA16(a[i], b[j], acc[i][j]);
        }
    }
    #pragma unroll
    for (int j = 0; j < 4; j++) {
        const int n = n0 + nb + j * 16 + l16;
        const float bv = bias[n];
        #pragma unroll
        for (int i = 0; i < 4; i++)
            #pragma unroll
            for (int r = 0; r < 4; r++) {
                const int m = m0 + mb + i * 16 + quad * 4 + r;
                out[(size_t)m * kDM + n] = (bf16)(acc[i][j][r] + bv);
            }
    }
}

// ---------------------------------------------------------------------------
// In-place multimodal 3D RoPE (unchanged from R1; verified correct).
// ---------------------------------------------------------------------------
__global__ __launch_bounds__(256) void rope_kernel(bf16* __restrict__ buf, int fast)
{
    const int gid = blockIdx.x * 256 + threadIdx.x;
    const int d = gid & 63;
    const int h = (gid >> 6) & 7;
    const int n = gid >> 9;
    int pt, ph, pw;
    if (fast) { pt = n >> 10; ph = (n >> 5) & 31; pw = n & 31; }
    else      { int tq = n >> 8; pt = (31 * tq) / 7; ph = 2 * ((n >> 4) & 15) + 1; pw = 2 * (n & 15) + 1; }
    const int p = (d < 16) ? pt : ((d < 40) ? ph : pw);
    const float angle = (float)p * exp2f((float)d * -0.20762050593045951f); // log2(1e4)/64
    const float c = cosf(angle), s = sinf(angle);
    const size_t i1 = (size_t)n * kDM + h * 128 + d;
    const float x1 = (float)buf[i1], x2 = (float)buf[i1 + 64];
    buf[i1]      = (bf16)(x1 * c - x2 * s);
    buf[i1 + 64] = (bf16)(x2 * c + x1 * s);
}

// ---------------------------------------------------------------------------
// Flash attention with 4-way key split. Block=(qb,h,z=t*4+sp), 256thr=4 waves.
// 64-key tiles; K via global_load_lds; V transposed in LDS with 16 extra
// "ones" rows so the l (row-sum of P) accumulates via MFMA (o[8]).
// Writes unnormalized O + (m,l) partials; combine kernel reduces splits.
// ---------------------------------------------------------------------------
__global__ __launch_bounds__(256) void attn_kernel(
    const bf16* __restrict__ qh, const bf16* __restrict__ kh,
    const bf16* __restrict__ vh, float* __restrict__ Opart, float* __restrict__ ml)
{
    __shared__ bf16 Ks[64 * 128];    // [key][d] unpadded (global_load_lds)
    __shared__ bf16 Vt[144][72];     // [d][key]; rows 128..143 = 1.0 (l-trick)
    __shared__ bf16 Ps[4][16][72];   // per-wave P: C-layout -> A-layout

    const int tid  = threadIdx.x;
    const int qb   = blockIdx.x, h = blockIdx.y, z = blockIdx.z;
    const int t    = z >> 2, sp = z & 3;
    const int wave = tid >> 6;
    const int lane = tid & 63;
    const int quad = lane >> 4, l16 = lane & 15;

    // ones rows (cols 0..63), written once, never overwritten
    for (int i = tid; i < 16 * 64; i += 256) Vt[128 + (i >> 6)][i & 63] = (bf16)1.0f;

    const int qrow = qb * 64 + wave * 16 + l16;
    const size_t qbase = ((size_t)(t * 256 + qrow)) * kDM + h * 128;
    bf16x8 aq[4];
    #pragma unroll
    for (int kb = 0; kb < 4; kb++)
        aq[kb] = *(const bf16x8*)&qh[qbase + kb * 32 + quad * 8];

    f32x4 o[9];
    #pragma unroll
    for (int j = 0; j < 9; j++) o[j] = zero4();
    float m_run[4];
    #pragma unroll
    for (int r = 0; r < 4; r++) m_run[r] = -1e30f;
    const float scale = 0.08838834764831845f;   // 1/sqrt(128)

    const int vrow = lane;        // V staging: wave's 64 lanes = 64 key rows
    const int vc8  = wave;        // wave -> d-chunk phase

    for (int kt = 0; kt < 16; kt++) {
        const int kbase = t * 4096 + sp * 1024 + kt * 64;
        __syncthreads();
        // K tile: 16 chunks of 1KB (4 rows each)
        #pragma unroll
        for (int i = 0; i < 4; i++) {
            const int c = wave * 4 + i;
            GLOAD_LDS16(&kh[(size_t)(kbase + c * 4 + (lane >> 4)) * kDM + h * 128 + (lane & 15) * 8],
                        &Ks[c * 512]);
        }
        // V tile transposed: wave handles d-chunks vc8+4i, all 64 key rows
        #pragma unroll
        for (int i = 0; i < 4; i++) {
            const int dc = vc8 + 4 * i;
            uint4 vv = *(const uint4*)&vh[(size_t)(kbase + vrow) * kDM + h * 128 + dc * 8];
            const bf16* vp = (const bf16*)&vv;
            #pragma unroll
            for (int j = 0; j < 8; j++) Vt[dc * 8 + j][vrow] = vp[j];
        }
        __syncthreads();

        // S = Q K^T : 16 q x 64 keys per wave
        f32x4 s[4];
        #pragma unroll
        for (int c = 0; c < 4; c++) s[c] = zero4();
        #pragma unroll
        for (int kb = 0; kb < 4; kb++) {
            #pragma unroll
            for (int c = 0; c < 4; c++) {
                bf16x8 b = *(const bf16x8*)&Ks[(c * 16 + l16) * 128 + kb * 32 + quad * 8];
                s[c] = MFMA16(aq[kb], b, s[c]);
            }
        }

        // online softmax (max via shfl; sum via MFMA ones-column)
        float alpha[4];
        #pragma unroll
        for (int r = 0; r < 4; r++) {
            float sv[4];
            #pragma unroll
            for (int c = 0; c < 4; c++) sv[c] = s[c][r] * scale;
            float mx = fmaxf(fmaxf(sv[0], sv[1]), fmaxf(sv[2], sv[3]));
            #pragma unroll
            for (int off = 1; off < 16; off <<= 1) mx = fmaxf(mx, __shfl_xor(mx, off));
            const float mn = fmaxf(m_run[r], mx);
            alpha[r] = __expf(m_run[r] - mn);
            m_run[r] = mn;
            #pragma unroll
            for (int c = 0; c < 4; c++)
                Ps[wave][quad * 4 + r][c * 16 + l16] = (bf16)__expf(sv[c] - mn);
        }
        #pragma unroll
        for (int j = 0; j < 9; j++)
            #pragma unroll
            for (int r = 0; r < 4; r++) o[j][r] *= alpha[r];
        // O += P V  (8 d-tiles + 1 l-tile), P round-trips LDS (wave-local)
        #pragma unroll
        for (int ks = 0; ks < 2; ks++) {
            bf16x8 pa = *(const bf16x8*)&Ps[wave][l16][ks * 32 + quad * 8];
            #pragma unroll
            for (int j = 0; j < 9; j++) {
                bf16x8 bv = *(const bf16x8*)&Vt[j * 16 + l16][ks * 32 + quad * 8];
                o[j] = MFMA16(pa, bv, o[j]);
            }
        }
    }

    // unnormalized partials
    #pragma unroll
    for (int r = 0; r < 4; r++) {
        const int srow = qb * 64 + wave * 16 + quad * 4 + r;
        const size_t pr = ((size_t)(z * 8 + h)) * 256 + srow;
        #pragma unroll
        for (int j = 0; j < 8; j++)
            Opart[pr * 128 + j * 16 + l16] = o[j][r];
        if (l16 == 0) { ml[pr * 2] = m_run[r]; ml[pr * 2 + 1] = o[8][r]; }
    }
}

// ---------------------------------------------------------------------------
// Combine 4 splits: O = sum O_sp*exp(m_sp-m*) / sum l_sp*exp(m_sp-m*)
// ---------------------------------------------------------------------------
__global__ __launch_bounds__(256) void combine_kernel(
    const float* __restrict__ Opart, const float* __restrict__ ml,
    float* __restrict__ out)
{
    const int tid = threadIdx.x;
    const int rid = blockIdx.x * 2 + (tid >> 7);
    const int d   = tid & 127;
    const int t = rid >> 11, h = (rid >> 8) & 7, srow = rid & 255;

    float mv[4], lv[4];
    #pragma unroll
    for (int sp = 0; sp < 4; sp++) {
        const size_t pr = ((size_t)((t * 4 + sp) * 8 + h)) * 256 + srow;
        float2 p = *(const float2*)&ml[pr * 2];
        mv[sp] = p.x; lv[sp] = p.y;
    }
    const float ms = fmaxf(fmaxf(mv[0], mv[1]), fmaxf(mv[2], mv[3]));
    float lsum = 0.f, acc = 0.f;
    #pragma unroll
    for (int sp = 0; sp < 4; sp++) {
        const size_t pr = ((size_t)((t * 4 + sp) * 8 + h)) * 256 + srow;
        const float w = __expf(mv[sp] - ms);
        lsum += lv[sp] * w;
        acc  += Opart[pr * 128 + d] * w;
    }
    out[((size_t)(t * 256 + srow)) * kDM + h * 128 + d] = acc / lsum;
}

// ---------------------------------------------------------------------------
extern "C" void kernel_launch(void* const* d_in, const int* in_sizes, int n_in,
                              void* d_out, int out_size, void* d_ws, size_t ws_size,
                              hipStream_t stream)
{
    const float* q  = (const float*)d_in[0];
    const float* k  = (const float*)d_in[1];
    const float* v  = (const float*)d_in[2];
    const float* Wq = (const float*)d_in[3];
    const float* bq = (const float*)d_in[4];
    const float* Wk = (const float*)d_in[5];
    const float* bk = (const float*)d_in[6];
    const float* Wv = (const float*)d_in[7];
    const float* bv = (const float*)d_in[8];
    float* out = (float*)d_out;

    // ws: qh 4MB | kh 64MB | vh 64MB | Wt x3 6MB | Opart 33.6MB | ml 0.6MB
    bf16* qh  = (bf16*)d_ws;
    bf16* kh  = qh + (size_t)2048 * 1024;
    bf16* vh  = kh + (size_t)32768 * 1024;
    bf16* Wqt = vh + (size_t)32768 * 1024;
    bf16* Wkt = Wqt + (size_t)1024 * 1024;
    bf16* Wvt = Wkt + (size_t)1024 * 1024;
    float* Opart = (float*)(Wvt + (size_t)1024 * 1024);
    float* ml    = Opart + (size_t)32 * 8 * 256 * 128;

    transpose_w<<<dim3(16, 16), 256, 0, stream>>>(Wq, Wqt);
    transpose_w<<<dim3(16, 16), 256, 0, stream>>>(Wk, Wkt);
    transpose_w<<<dim3(16, 16), 256, 0, stream>>>(Wv, Wvt);
    gemm_bt<<<dim3(8, 16),  256, 0, stream>>>(q, Wqt, bq, qh);
    gemm_bt<<<dim3(8, 256), 256, 0, stream>>>(k, Wkt, bk, kh);
    gemm_bt<<<dim3(8, 256), 256, 0, stream>>>(v, Wvt, bv, vh);
    rope_kernel<<<4096,  256, 0, stream>>>(qh, 0);
    rope_kernel<<<65536, 256, 0, stream>>>(kh, 1);
    attn_kernel<<<dim3(4, 8, 32), 256, 0, stream>>>(qh, kh, vh, Opart, ml);
    combine_kernel<<<8192, 256, 0, stream>>>(Opart, ml, out);
}

// Round 3
// 846.508 us; speedup vs baseline: 1.8905x; 1.0659x over previous
//
#include <hip/hip_runtime.h>

typedef __bf16 bf16;
typedef __bf16 bf16x8 __attribute__((ext_vector_type(8)));
typedef float  f32x4  __attribute__((ext_vector_type(4)));

#define MFMA16(a, b, c) __builtin_amdgcn_mfma_f32_16x16x32_bf16((a), (b), (c), 0, 0, 0)

// async global->LDS, 16B per lane; LDS dest = wave-uniform base + lane*16
#define GLOAD_LDS16(gptr, lptr)                                              \
    __builtin_amdgcn_global_load_lds(                                        \
        (const __attribute__((address_space(1))) unsigned int*)(gptr),       \
        (__attribute__((address_space(3))) unsigned int*)(lptr), 16, 0, 0)

constexpr int kDM = 1024;
constexpr int kNTOK = 32768;   // V token count (vt row stride)

static __device__ inline f32x4 zero4() { f32x4 z = {0.f, 0.f, 0.f, 0.f}; return z; }

// ---------------------------------------------------------------------------
// W fp32 [k][n] -> Wt bf16 [n][k]  (64x64 LDS-tiled transpose+convert)
// ---------------------------------------------------------------------------
__global__ __launch_bounds__(256) void transpose_w(
    const float* __restrict__ W, bf16* __restrict__ Wt)
{
    __shared__ bf16 T[64][68];
    const int tid = threadIdx.x;
    const int n0 = blockIdx.x * 64, k0 = blockIdx.y * 64;
    #pragma unroll
    for (int i = 0; i < 4; i++) {
        const int kk = (tid >> 4) + i * 16, nn4 = (tid & 15) * 4;
        float4 v = *(const float4*)&W[(size_t)(k0 + kk) * kDM + n0 + nn4];
        T[nn4 + 0][kk] = (bf16)v.x; T[nn4 + 1][kk] = (bf16)v.y;
        T[nn4 + 2][kk] = (bf16)v.z; T[nn4 + 3][kk] = (bf16)v.w;
    }
    __syncthreads();
    #pragma unroll
    for (int i = 0; i < 4; i++) {
        const int nn = (tid >> 4) + i * 16, kc = (tid & 15) * 4;
        *(ushort4*)&Wt[(size_t)(n0 + nn) * kDM + k0 + kc] = *(const ushort4*)&T[nn][kc];
    }
}

// ---------------------------------------------------------------------------
// GEMM: out = X_fp32[M][1024] @ Wt_bf16[N][K]^T + bias
// 128x128 tile, BK=64, 4 waves 2x2 (each 64x64). A fp32 via global_load_lds,
// converted on frag read; B bf16 via global_load_lds (row-contiguous).
// grid.x = m-block, grid.y = n-block(8): gridDim.x % 8 == 0 means all 8
// n-blocks of an m-tile land on the SAME XCD -> X fetched once from HBM.
// TRANSPOSED: write out[n0+n][m] (token-contiguous V^T), via LDS transpose.
// ---------------------------------------------------------------------------
template <bool TRANSPOSED>
__global__ __launch_bounds__(256) void gemm_bt(
    const float* __restrict__ X, const bf16* __restrict__ Wt,
    const float* __restrict__ bias, bf16* __restrict__ out)
{
    __shared__ char smem[49152];
    float* Asf = (float*)smem;            // [128][64] fp32 (32KB)
    bf16*  Bsb = (bf16*)(smem + 32768);   // [128][64] bf16 (16KB)

    const int tid  = threadIdx.x;
    const int m0   = blockIdx.x * 128;
    const int n0   = blockIdx.y * 128;
    const int wave = tid >> 6;
    const int lane = tid & 63;
    const int quad = lane >> 4, l16 = lane & 15;
    const int mb   = (wave & 1) * 64, nb = (wave >> 1) * 64;

    f32x4 acc[4][4];
    #pragma unroll
    for (int i = 0; i < 4; i++)
        #pragma unroll
        for (int j = 0; j < 4; j++) acc[i][j] = zero4();

    for (int k0 = 0; k0 < kDM; k0 += 64) {
        __syncthreads();
        #pragma unroll
        for (int i = 0; i < 8; i++) {   // A: 32 chunks of 1KB (4 fp32 rows)
            const int c = wave * 8 + i;
            GLOAD_LDS16(&X[(size_t)(m0 + c * 4 + (lane >> 4)) * kDM + k0 + (lane & 15) * 4],
                        &Asf[c * 256]);
        }
        #pragma unroll
        for (int i = 0; i < 4; i++) {   // B: 16 chunks of 1KB (8 bf16 rows)
            const int c = wave * 4 + i;
            GLOAD_LDS16(&Wt[(size_t)(n0 + c * 8 + (lane >> 3)) * kDM + k0 + (lane & 7) * 8],
                        &Bsb[c * 512]);
        }
        __syncthreads();
        #pragma unroll
        for (int ks = 0; ks < 2; ks++) {
            bf16x8 a[4], b[4];
            #pragma unroll
            for (int i = 0; i < 4; i++) {
                const float* p = &Asf[(mb + i * 16 + l16) * 64 + ks * 32 + quad * 8];
                f32x4 u0 = *(const f32x4*)p;
                f32x4 u1 = *(const f32x4*)(p + 4);
                #pragma unroll
                for (int e = 0; e < 4; e++) { a[i][e] = (bf16)u0[e]; a[i][4 + e] = (bf16)u1[e]; }
            }
            #pragma unroll
            for (int j = 0; j < 4; j++)
                b[j] = *(const bf16x8*)&Bsb[(nb + j * 16 + l16) * 64 + ks * 32 + quad * 8];
            #pragma unroll
            for (int i = 0; i < 4; i++)
                #pragma unroll
                for (int j = 0; j < 4; j++)
                    acc[i][j] = MFMA16(a[i], b[j], acc[i][j]);
        }
    }

    if (!TRANSPOSED) {
        #pragma unroll
        for (int j = 0; j < 4; j++) {
            const int n = n0 + nb + j * 16 + l16;
            const float bv = bias[n];
            #pragma unroll
            for (int i = 0; i < 4; i++)
                #pragma unroll
                for (int r = 0; r < 4; r++) {
                    const int m = m0 + mb + i * 16 + quad * 4 + r;
                    out[(size_t)m * kDM + n] = (bf16)(acc[i][j][r] + bv);
                }
        }
    } else {
        __syncthreads();                     // done with Asf/Bsb
        bf16* T = (bf16*)smem;               // [128][136] bf16 (34.8KB)
        #pragma unroll
        for (int j = 0; j < 4; j++) {
            const int n = nb + j * 16 + l16;
            const float bv = bias[n0 + n];
            #pragma unroll
            for (int i = 0; i < 4; i++) {
                const int m = mb + i * 16 + quad * 4;
                bf16 tmp[4];
                #pragma unroll
                for (int r = 0; r < 4; r++) tmp[r] = (bf16)(acc[i][j][r] + bv);
                *(ushort4*)&T[n * 136 + m] = *(const ushort4*)tmp;
            }
        }
        __syncthreads();
        const int row = tid >> 1, seg = (tid & 1) * 64;
        #pragma unroll
        for (int kk = 0; kk < 8; kk++)
            *(uint4*)&out[(size_t)(n0 + row) * kNTOK + m0 + seg + kk * 8] =
                *(const uint4*)&T[row * 136 + seg + kk * 8];
    }
}

// ---------------------------------------------------------------------------
// In-place multimodal 3D RoPE (verified R1/R2).
// ---------------------------------------------------------------------------
__global__ __launch_bounds__(256) void rope_kernel(bf16* __restrict__ buf, int fast)
{
    const int gid = blockIdx.x * 256 + threadIdx.x;
    const int d = gid & 63;
    const int h = (gid >> 6) & 7;
    const int n = gid >> 9;
    int pt, ph, pw;
    if (fast) { pt = n >> 10; ph = (n >> 5) & 31; pw = n & 31; }
    else      { int tq = n >> 8; pt = (31 * tq) / 7; ph = 2 * ((n >> 4) & 15) + 1; pw = 2 * (n & 15) + 1; }
    const int p = (d < 16) ? pt : ((d < 40) ? ph : pw);
    const float angle = (float)p * exp2f((float)d * -0.20762050593045951f); // log2(1e4)/64
    const float c = cosf(angle), s = sinf(angle);
    const size_t i1 = (size_t)n * kDM + h * 128 + d;
    const float x1 = (float)buf[i1], x2 = (float)buf[i1 + 64];
    buf[i1]      = (bf16)(x1 * c - x2 * s);
    buf[i1 + 64] = (bf16)(x2 * c + x1 * s);
}

// ---------------------------------------------------------------------------
// Flash attention, 8-way key split. Block=(qb,h,z=t*8+sp), 256thr=4 waves.
// 64-key tiles; K and V^T both staged via global_load_lds (V^T from vt,
// pre-transposed by the V GEMM). Ones rows 128..143 of Vs give l via MFMA.
// ---------------------------------------------------------------------------
__global__ __launch_bounds__(256) void attn_kernel(
    const bf16* __restrict__ qh, const bf16* __restrict__ kh,
    const bf16* __restrict__ vt, float* __restrict__ Opart, float* __restrict__ ml)
{
    __shared__ bf16 Ks[64 * 128];    // [key][d]
    __shared__ bf16 Vs[144 * 64];    // [d][key]; rows 128..143 = 1.0 (l-trick)
    __shared__ bf16 Ps[4][16][72];   // per-wave P: C-layout -> A-layout

    const int tid  = threadIdx.x;
    const int qb   = blockIdx.x, h = blockIdx.y, z = blockIdx.z;
    const int t    = z >> 3, sp = z & 7;
    const int wave = tid >> 6;
    const int lane = tid & 63;
    const int quad = lane >> 4, l16 = lane & 15;

    for (int i = tid; i < 16 * 64; i += 256) Vs[(128 + (i >> 6)) * 64 + (i & 63)] = (bf16)1.0f;

    const int qrow = qb * 64 + wave * 16 + l16;
    const size_t qbase = ((size_t)(t * 256 + qrow)) * kDM + h * 128;
    bf16x8 aq[4];
    #pragma unroll
    for (int kb = 0; kb < 4; kb++)
        aq[kb] = *(const bf16x8*)&qh[qbase + kb * 32 + quad * 8];

    f32x4 o[9];
    #pragma unroll
    for (int j = 0; j < 9; j++) o[j] = zero4();
    float m_run[4];
    #pragma unroll
    for (int r = 0; r < 4; r++) m_run[r] = -1e30f;
    const float scale = 0.08838834764831845f;   // 1/sqrt(128)

    for (int kt = 0; kt < 8; kt++) {
        const int kbase = t * 4096 + sp * 512 + kt * 64;
        __syncthreads();
        #pragma unroll
        for (int i = 0; i < 4; i++) {   // K: 16 chunks (4 key rows each)
            const int c = wave * 4 + i;
            GLOAD_LDS16(&kh[(size_t)(kbase + c * 4 + (lane >> 4)) * kDM + h * 128 + (lane & 15) * 8],
                        &Ks[c * 512]);
        }
        #pragma unroll
        for (int i = 0; i < 4; i++) {   // V^T: 16 chunks (8 d rows x 64 keys)
            const int c = wave * 4 + i;
            GLOAD_LDS16(&vt[(size_t)(h * 128 + c * 8 + (lane >> 3)) * kNTOK + kbase + (lane & 7) * 8],
                        &Vs[c * 512]);
        }
        __syncthreads();

        // S = Q K^T : 16 q x 64 keys per wave
        f32x4 s[4];
        #pragma unroll
        for (int c = 0; c < 4; c++) s[c] = zero4();
        #pragma unroll
        for (int kb = 0; kb < 4; kb++) {
            #pragma unroll
            for (int c = 0; c < 4; c++) {
                bf16x8 b = *(const bf16x8*)&Ks[(c * 16 + l16) * 128 + kb * 32 + quad * 8];
                s[c] = MFMA16(aq[kb], b, s[c]);
            }
        }

        // online softmax (max via shfl; sum via MFMA ones rows)
        float alpha[4];
        #pragma unroll
        for (int r = 0; r < 4; r++) {
            float sv[4];
            #pragma unroll
            for (int c = 0; c < 4; c++) sv[c] = s[c][r] * scale;
            float mx = fmaxf(fmaxf(sv[0], sv[1]), fmaxf(sv[2], sv[3]));
            #pragma unroll
            for (int off = 1; off < 16; off <<= 1) mx = fmaxf(mx, __shfl_xor(mx, off));
            const float mn = fmaxf(m_run[r], mx);
            alpha[r] = __expf(m_run[r] - mn);
            m_run[r] = mn;
            #pragma unroll
            for (int c = 0; c < 4; c++)
                Ps[wave][quad * 4 + r][c * 16 + l16] = (bf16)__expf(sv[c] - mn);
        }
        #pragma unroll
        for (int j = 0; j < 9; j++)
            #pragma unroll
            for (int r = 0; r < 4; r++) o[j][r] *= alpha[r];
        #pragma unroll
        for (int ks = 0; ks < 2; ks++) {
            bf16x8 pa = *(const bf16x8*)&Ps[wave][l16][ks * 32 + quad * 8];
            #pragma unroll
            for (int j = 0; j < 9; j++) {
                bf16x8 bv = *(const bf16x8*)&Vs[(j * 16 + l16) * 64 + ks * 32 + quad * 8];
                o[j] = MFMA16(pa, bv, o[j]);
            }
        }
    }

    #pragma unroll
    for (int r = 0; r < 4; r++) {
        const int srow = qb * 64 + wave * 16 + quad * 4 + r;
        const size_t pr = ((size_t)(z * 8 + h)) * 256 + srow;
        #pragma unroll
        for (int j = 0; j < 8; j++)
            Opart[pr * 128 + j * 16 + l16] = o[j][r];
        if (l16 == 0) { ml[pr * 2] = m_run[r]; ml[pr * 2 + 1] = o[8][r]; }
    }
}

// ---------------------------------------------------------------------------
// Combine 8 splits: O = sum O_sp*exp(m_sp-m*) / sum l_sp*exp(m_sp-m*)
// ---------------------------------------------------------------------------
__global__ __launch_bounds__(256) void combine_kernel(
    const float* __restrict__ Opart, const float* __restrict__ ml,
    float* __restrict__ out)
{
    const int tid = threadIdx.x;
    const int rid = blockIdx.x * 2 + (tid >> 7);
    const int d   = tid & 127;
    const int t = rid >> 11, h = (rid >> 8) & 7, srow = rid & 255;

    float mv[8], lv[8];
    #pragma unroll
    for (int sp = 0; sp < 8; sp++) {
        const size_t pr = ((size_t)((t * 8 + sp) * 8 + h)) * 256 + srow;
        float2 p = *(const float2*)&ml[pr * 2];
        mv[sp] = p.x; lv[sp] = p.y;
    }
    float ms = mv[0];
    #pragma unroll
    for (int sp = 1; sp < 8; sp++) ms = fmaxf(ms, mv[sp]);
    float lsum = 0.f, acc = 0.f;
    #pragma unroll
    for (int sp = 0; sp < 8; sp++) {
        const size_t pr = ((size_t)((t * 8 + sp) * 8 + h)) * 256 + srow;
        const float w = __expf(mv[sp] - ms);
        lsum += lv[sp] * w;
        acc  += Opart[pr * 128 + d] * w;
    }
    out[((size_t)(t * 256 + srow)) * kDM + h * 128 + d] = acc / lsum;
}

// ---------------------------------------------------------------------------
extern "C" void kernel_launch(void* const* d_in, const int* in_sizes, int n_in,
                              void* d_out, int out_size, void* d_ws, size_t ws_size,
                              hipStream_t stream)
{
    const float* q  = (const float*)d_in[0];
    const float* k  = (const float*)d_in[1];
    const float* v  = (const float*)d_in[2];
    const float* Wq = (const float*)d_in[3];
    const float* bq = (const float*)d_in[4];
    const float* Wk = (const float*)d_in[5];
    const float* bk = (const float*)d_in[6];
    const float* Wv = (const float*)d_in[7];
    const float* bv = (const float*)d_in[8];
    float* out = (float*)d_out;

    // ws: qh 4MB | kh 64MB | vt 64MB | Wt x3 6MB | Opart 67MB | ml 1.1MB
    bf16* qh  = (bf16*)d_ws;
    bf16* kh  = qh + (size_t)2048 * 1024;
    bf16* vt  = kh + (size_t)32768 * 1024;
    bf16* Wqt = vt + (size_t)32768 * 1024;
    bf16* Wkt = Wqt + (size_t)1024 * 1024;
    bf16* Wvt = Wkt + (size_t)1024 * 1024;
    float* Opart = (float*)(Wvt + (size_t)1024 * 1024);
    float* ml    = Opart + (size_t)64 * 8 * 256 * 128;

    transpose_w<<<dim3(16, 16), 256, 0, stream>>>(Wq, Wqt);
    transpose_w<<<dim3(16, 16), 256, 0, stream>>>(Wk, Wkt);
    transpose_w<<<dim3(16, 16), 256, 0, stream>>>(Wv, Wvt);
    gemm_bt<false><<<dim3(16, 8),  256, 0, stream>>>(q, Wqt, bq, qh);
    gemm_bt<false><<<dim3(256, 8), 256, 0, stream>>>(k, Wkt, bk, kh);
    gemm_bt<true><<<dim3(256, 8),  256, 0, stream>>>(v, Wvt, bv, vt);
    rope_kernel<<<4096,  256, 0, stream>>>(qh, 0);
    rope_kernel<<<65536, 256, 0, stream>>>(kh, 1);
    attn_kernel<<<dim3(4, 8, 64), 256, 0, stream>>>(qh, kh, vt, Opart, ml);
    combine_kernel<<<8192, 256, 0, stream>>>(Opart, ml, out);
}

// Round 4
// 701.617 us; speedup vs baseline: 2.2809x; 1.2065x over previous
//
#include <hip/hip_runtime.h>

typedef __bf16 bf16;
typedef __bf16 bf16x8 __attribute__((ext_vector_type(8)));
typedef float  f32x4  __attribute__((ext_vector_type(4)));

#define MFMA16(a, b, c) __builtin_amdgcn_mfma_f32_16x16x32_bf16((a), (b), (c), 0, 0, 0)

// async global->LDS, 16B per lane; LDS dest = wave-uniform base + lane*16
#define GLOAD_LDS16(gptr, lptr)                                              \
    __builtin_amdgcn_global_load_lds(                                        \
        (const __attribute__((address_space(1))) unsigned int*)(gptr),       \
        (__attribute__((address_space(3))) unsigned int*)(lptr), 16, 0, 0)

constexpr int kDM = 1024;
constexpr int kNTOK = 32768;   // V token count (vt row stride)

static __device__ inline f32x4 zero4() { f32x4 z = {0.f, 0.f, 0.f, 0.f}; return z; }

// ---------------------------------------------------------------------------
// fp32 -> bf16 convert (8 elements / thread, float4 loads, uint4 store)
// ---------------------------------------------------------------------------
__global__ __launch_bounds__(256) void convert_bf16(
    const float* __restrict__ in, bf16* __restrict__ out)
{
    const size_t i = ((size_t)blockIdx.x * 256 + threadIdx.x) * 8;
    float4 a = *(const float4*)&in[i];
    float4 b = *(const float4*)&in[i + 4];
    bf16 t[8];
    t[0] = (bf16)a.x; t[1] = (bf16)a.y; t[2] = (bf16)a.z; t[3] = (bf16)a.w;
    t[4] = (bf16)b.x; t[5] = (bf16)b.y; t[6] = (bf16)b.z; t[7] = (bf16)b.w;
    *(uint4*)&out[i] = *(const uint4*)t;
}

// ---------------------------------------------------------------------------
// W fp32 [k][n] -> Wt bf16 [n][k]  (64x64 LDS-tiled transpose+convert)
// ---------------------------------------------------------------------------
__global__ __launch_bounds__(256) void transpose_w(
    const float* __restrict__ W, bf16* __restrict__ Wt)
{
    __shared__ bf16 T[64][68];
    const int tid = threadIdx.x;
    const int n0 = blockIdx.x * 64, k0 = blockIdx.y * 64;
    #pragma unroll
    for (int i = 0; i < 4; i++) {
        const int kk = (tid >> 4) + i * 16, nn4 = (tid & 15) * 4;
        float4 v = *(const float4*)&W[(size_t)(k0 + kk) * kDM + n0 + nn4];
        T[nn4 + 0][kk] = (bf16)v.x; T[nn4 + 1][kk] = (bf16)v.y;
        T[nn4 + 2][kk] = (bf16)v.z; T[nn4 + 3][kk] = (bf16)v.w;
    }
    __syncthreads();
    #pragma unroll
    for (int i = 0; i < 4; i++) {
        const int nn = (tid >> 4) + i * 16, kc = (tid & 15) * 4;
        *(ushort4*)&Wt[(size_t)(n0 + nn) * kDM + k0 + kc] = *(const ushort4*)&T[nn][kc];
    }
}

// ---------------------------------------------------------------------------
// GEMM: out = Xb_bf16[M][1024] @ Wt_bf16[N][K]^T + bias
// 128x128 tile, BK=64, 4 waves 2x2. Both tiles via global_load_lds (16KB each)
// with XOR column swizzle: LDS(row, chunk) = G(row, chunk ^ (row&7)) so that
// fragment reads (rows differ by l16) spread across all 8 bank groups (2-way
// aliasing = free) instead of 16-way same-bank conflicts.
// 1D grid, XCD swizzle: xcd = b&7 owns contiguous m-tiles, n fastest -> each
// m-tile's 8 n-blocks are temporally adjacent on one XCD (X fetched once).
// TRANSPOSED: write out[n][m] (token-contiguous V^T) via LDS transpose.
// ---------------------------------------------------------------------------
template <bool TRANSPOSED>
__global__ __launch_bounds__(256) void gemm_bt(
    const bf16* __restrict__ Xb, const bf16* __restrict__ Wt,
    const float* __restrict__ bias, bf16* __restrict__ out, int mtiles_per_xcd)
{
    __shared__ char smem[TRANSPOSED ? 34816 : 32768];
    bf16* Ab = (bf16*)smem;             // [128][64] bf16, XOR-swizzled chunks
    bf16* Bb = (bf16*)(smem + 16384);   // [128][64] bf16, XOR-swizzled chunks

    const int b    = blockIdx.x;
    const int xcd  = b & 7;
    const int s    = b >> 3;
    const int m0   = (xcd * mtiles_per_xcd + (s >> 3)) * 128;
    const int n0   = (s & 7) * 128;
    const int tid  = threadIdx.x;
    const int wave = tid >> 6;
    const int lane = tid & 63;
    const int quad = lane >> 4, l16 = lane & 15;
    const int mb   = (wave & 1) * 64, nb = (wave >> 1) * 64;
    const int r8   = lane >> 3, j8 = lane & 7;
    const int sw8  = (j8 ^ r8) * 8;       // swizzled element offset for staging

    f32x4 acc[4][4];
    #pragma unroll
    for (int i = 0; i < 4; i++)
        #pragma unroll
        for (int j = 0; j < 4; j++) acc[i][j] = zero4();

    for (int k0 = 0; k0 < kDM; k0 += 64) {
        __syncthreads();
        #pragma unroll
        for (int i = 0; i < 4; i++) {   // A: 16 chunks of 1KB (8 rows x 8 c16)
            const int c = wave * 4 + i;
            GLOAD_LDS16(&Xb[(size_t)(m0 + c * 8 + r8) * kDM + k0 + sw8], &Ab[c * 512]);
        }
        #pragma unroll
        for (int i = 0; i < 4; i++) {   // B: 16 chunks of 1KB
            const int c = wave * 4 + i;
            GLOAD_LDS16(&Wt[(size_t)(n0 + c * 8 + r8) * kDM + k0 + sw8], &Bb[c * 512]);
        }
        __syncthreads();
        #pragma unroll
        for (int ks = 0; ks < 2; ks++) {
            bf16x8 a[4], bfr[4];
            #pragma unroll
            for (int i = 0; i < 4; i++) {
                const int m = mb + i * 16 + l16;
                a[i] = *(const bf16x8*)&Ab[m * 64 + (((ks * 4 + quad) ^ (l16 & 7)) * 8)];
            }
            #pragma unroll
            for (int j = 0; j < 4; j++) {
                const int n = nb + j * 16 + l16;
                bfr[j] = *(const bf16x8*)&Bb[n * 64 + (((ks * 4 + quad) ^ (l16 & 7)) * 8)];
            }
            #pragma unroll
            for (int i = 0; i < 4; i++)
                #pragma unroll
                for (int j = 0; j < 4; j++)
                    acc[i][j] = MFMA16(a[i], bfr[j], acc[i][j]);
        }
    }

    if (!TRANSPOSED) {
        #pragma unroll
        for (int j = 0; j < 4; j++) {
            const int n = n0 + nb + j * 16 + l16;
            const float bv = bias[n];
            #pragma unroll
            for (int i = 0; i < 4; i++)
                #pragma unroll
                for (int r = 0; r < 4; r++) {
                    const int m = m0 + mb + i * 16 + quad * 4 + r;
                    out[(size_t)m * kDM + n] = (bf16)(acc[i][j][r] + bv);
                }
        }
    } else {
        __syncthreads();                     // done with Ab/Bb
        bf16* T = (bf16*)smem;               // [128][136] bf16
        #pragma unroll
        for (int j = 0; j < 4; j++) {
            const int n = nb + j * 16 + l16;
            const float bv = bias[n0 + n];
            #pragma unroll
            for (int i = 0; i < 4; i++) {
                const int m = mb + i * 16 + quad * 4;
                bf16 tmp[4];
                #pragma unroll
                for (int r = 0; r < 4; r++) tmp[r] = (bf16)(acc[i][j][r] + bv);
                *(ushort4*)&T[n * 136 + m] = *(const ushort4*)tmp;
            }
        }
        __syncthreads();
        const int row = tid >> 1, seg = (tid & 1) * 64;
        #pragma unroll
        for (int kk = 0; kk < 8; kk++)
            *(uint4*)&out[(size_t)(n0 + row) * kNTOK + m0 + seg + kk * 8] =
                *(const uint4*)&T[row * 136 + seg + kk * 8];
    }
}

// ---------------------------------------------------------------------------
// In-place multimodal 3D RoPE (verified R1-R3).
// ---------------------------------------------------------------------------
__global__ __launch_bounds__(256) void rope_kernel(bf16* __restrict__ buf, int fast)
{
    const int gid = blockIdx.x * 256 + threadIdx.x;
    const int d = gid & 63;
    const int h = (gid >> 6) & 7;
    const int n = gid >> 9;
    int pt, ph, pw;
    if (fast) { pt = n >> 10; ph = (n >> 5) & 31; pw = n & 31; }
    else      { int tq = n >> 8; pt = (31 * tq) / 7; ph = 2 * ((n >> 4) & 15) + 1; pw = 2 * (n & 15) + 1; }
    const int p = (d < 16) ? pt : ((d < 40) ? ph : pw);
    const float angle = (float)p * exp2f((float)d * -0.20762050593045951f); // log2(1e4)/64
    const float c = cosf(angle), s = sinf(angle);
    const size_t i1 = (size_t)n * kDM + h * 128 + d;
    const float x1 = (float)buf[i1], x2 = (float)buf[i1 + 64];
    buf[i1]      = (bf16)(x1 * c - x2 * s);
    buf[i1 + 64] = (bf16)(x2 * c + x1 * s);
}

// ---------------------------------------------------------------------------
// Flash attention, 8-way key split. Grid (z=64, h=8, qb=4): the 4 qb-blocks
// sharing one (z,h) K/V slice are 512 apart in linear id (512%8==0) -> same
// XCD -> L2 reuse. K and V^T staged via global_load_lds with XOR swizzle
// (same scheme as GEMM). Ones rows 128..143 of Vs give l via MFMA.
// ---------------------------------------------------------------------------
__global__ __launch_bounds__(256) void attn_kernel(
    const bf16* __restrict__ qh, const bf16* __restrict__ kh,
    const bf16* __restrict__ vt, float* __restrict__ Opart, float* __restrict__ ml)
{
    __shared__ bf16 Ks[64 * 128];    // [key][d], chunk-swizzled by key&15
    __shared__ bf16 Vs[144 * 64];    // [d][key], chunk-swizzled by d&7; rows 128+ = 1.0
    __shared__ bf16 Ps[4][16][72];   // per-wave P: C-layout -> A-layout

    const int tid  = threadIdx.x;
    const int z    = blockIdx.x, h = blockIdx.y, qb = blockIdx.z;
    const int t    = z >> 3, sp = z & 7;
    const int wave = tid >> 6;
    const int lane = tid & 63;
    const int quad = lane >> 4, l16 = lane & 15;

    for (int i = tid; i < 16 * 64; i += 256) Vs[(128 + (i >> 6)) * 64 + (i & 63)] = (bf16)1.0f;

    const int qrow = qb * 64 + wave * 16 + l16;
    const size_t qbase = ((size_t)(t * 256 + qrow)) * kDM + h * 128;
    bf16x8 aq[4];
    #pragma unroll
    for (int kb = 0; kb < 4; kb++)
        aq[kb] = *(const bf16x8*)&qh[qbase + kb * 32 + quad * 8];

    f32x4 o[9];
    #pragma unroll
    for (int j = 0; j < 9; j++) o[j] = zero4();
    float m_run[4];
    #pragma unroll
    for (int r = 0; r < 4; r++) m_run[r] = -1e30f;
    const float scale = 0.08838834764831845f;   // 1/sqrt(128)

    const int r16 = lane >> 4, j16 = lane & 15;  // K staging coords (4 rows x 16 c16)
    const int r8  = lane >> 3, j8  = lane & 7;   // V staging coords (8 rows x 8 c16)

    for (int kt = 0; kt < 8; kt++) {
        const int kbase = t * 4096 + sp * 512 + kt * 64;
        __syncthreads();
        #pragma unroll
        for (int i = 0; i < 4; i++) {   // K: 16 chunks (4 key rows each)
            const int c = wave * 4 + i;
            const int krow = c * 4 + r16;
            GLOAD_LDS16(&kh[(size_t)(kbase + krow) * kDM + h * 128 + ((j16 ^ (krow & 15)) * 8)],
                        &Ks[c * 512]);
        }
        #pragma unroll
        for (int i = 0; i < 4; i++) {   // V^T: 16 chunks (8 d rows x 64 keys)
            const int c = wave * 4 + i;
            GLOAD_LDS16(&vt[(size_t)(h * 128 + c * 8 + r8) * kNTOK + kbase + ((j8 ^ r8) * 8)],
                        &Vs[c * 512]);
        }
        __syncthreads();

        // S = Q K^T : 16 q x 64 keys per wave
        f32x4 s[4];
        #pragma unroll
        for (int c = 0; c < 4; c++) s[c] = zero4();
        #pragma unroll
        for (int kb = 0; kb < 4; kb++) {
            #pragma unroll
            for (int c = 0; c < 4; c++) {
                bf16x8 b = *(const bf16x8*)&Ks[(c * 16 + l16) * 128 + (((kb * 4 + quad) ^ l16) * 8)];
                s[c] = MFMA16(aq[kb], b, s[c]);
            }
        }

        // online softmax (max via shfl; sum via MFMA ones rows)
        float alpha[4];
        #pragma unroll
        for (int r = 0; r < 4; r++) {
            float sv[4];
            #pragma unroll
            for (int c = 0; c < 4; c++) sv[c] = s[c][r] * scale;
            float mx = fmaxf(fmaxf(sv[0], sv[1]), fmaxf(sv[2], sv[3]));
            #pragma unroll
            for (int off = 1; off < 16; off <<= 1) mx = fmaxf(mx, __shfl_xor(mx, off));
            const float mn = fmaxf(m_run[r], mx);
            alpha[r] = __expf(m_run[r] - mn);
            m_run[r] = mn;
            #pragma unroll
            for (int c = 0; c < 4; c++)
                Ps[wave][quad * 4 + r][c * 16 + l16] = (bf16)__expf(sv[c] - mn);
        }
        #pragma unroll
        for (int j = 0; j < 9; j++)
            #pragma unroll
            for (int r = 0; r < 4; r++) o[j][r] *= alpha[r];
        #pragma unroll
        for (int ks = 0; ks < 2; ks++) {
            bf16x8 pa = *(const bf16x8*)&Ps[wave][l16][ks * 32 + quad * 8];
            #pragma unroll
            for (int j = 0; j < 9; j++) {
                bf16x8 bv = *(const bf16x8*)&Vs[(j * 16 + l16) * 64 + (((ks * 4 + quad) ^ (l16 & 7)) * 8)];
                o[j] = MFMA16(pa, bv, o[j]);
            }
        }
    }

    #pragma unroll
    for (int r = 0; r < 4; r++) {
        const int srow = qb * 64 + wave * 16 + quad * 4 + r;
        const size_t pr = ((size_t)(z * 8 + h)) * 256 + srow;
        #pragma unroll
        for (int j = 0; j < 8; j++)
            Opart[pr * 128 + j * 16 + l16] = o[j][r];
        if (l16 == 0) { ml[pr * 2] = m_run[r]; ml[pr * 2 + 1] = o[8][r]; }
    }
}

// ---------------------------------------------------------------------------
// Combine 8 splits: O = sum O_sp*exp(m_sp-m*) / sum l_sp*exp(m_sp-m*)
// ---------------------------------------------------------------------------
__global__ __launch_bounds__(256) void combine_kernel(
    const float* __restrict__ Opart, const float* __restrict__ ml,
    float* __restrict__ out)
{
    const int tid = threadIdx.x;
    const int rid = blockIdx.x * 2 + (tid >> 7);
    const int d   = tid & 127;
    const int t = rid >> 11, h = (rid >> 8) & 7, srow = rid & 255;

    float mv[8], lv[8];
    #pragma unroll
    for (int sp = 0; sp < 8; sp++) {
        const size_t pr = ((size_t)((t * 8 + sp) * 8 + h)) * 256 + srow;
        float2 p = *(const float2*)&ml[pr * 2];
        mv[sp] = p.x; lv[sp] = p.y;
    }
    float ms = mv[0];
    #pragma unroll
    for (int sp = 1; sp < 8; sp++) ms = fmaxf(ms, mv[sp]);
    float lsum = 0.f, acc = 0.f;
    #pragma unroll
    for (int sp = 0; sp < 8; sp++) {
        const size_t pr = ((size_t)((t * 8 + sp) * 8 + h)) * 256 + srow;
        const float w = __expf(mv[sp] - ms);
        lsum += lv[sp] * w;
        acc  += Opart[pr * 128 + d] * w;
    }
    out[((size_t)(t * 256 + srow)) * kDM + h * 128 + d] = acc / lsum;
}

// ---------------------------------------------------------------------------
extern "C" void kernel_launch(void* const* d_in, const int* in_sizes, int n_in,
                              void* d_out, int out_size, void* d_ws, size_t ws_size,
                              hipStream_t stream)
{
    const float* q  = (const float*)d_in[0];
    const float* k  = (const float*)d_in[1];
    const float* v  = (const float*)d_in[2];
    const float* Wq = (const float*)d_in[3];
    const float* bq = (const float*)d_in[4];
    const float* Wk = (const float*)d_in[5];
    const float* bk = (const float*)d_in[6];
    const float* Wv = (const float*)d_in[7];
    const float* bv = (const float*)d_in[8];
    float* out = (float*)d_out;

    // ws (bf16 elems): qh 4MB | kh 64MB | vt 64MB | Wt x3 6MB | qb 4MB |
    // kb 64MB | vb 64MB   (Opart/ml OVERLAP kb/vb: converts+gemms consume
    // kb/vb strictly before attn writes Opart — stream-ordered, safe)
    bf16* qh  = (bf16*)d_ws;
    bf16* kh  = qh + (size_t)2048 * 1024;
    bf16* vt  = kh + (size_t)32768 * 1024;
    bf16* Wqt = vt + (size_t)32768 * 1024;
    bf16* Wkt = Wqt + (size_t)1024 * 1024;
    bf16* Wvt = Wkt + (size_t)1024 * 1024;
    bf16* qb_  = Wvt + (size_t)1024 * 1024;
    bf16* kb_  = qb_ + (size_t)2048 * 1024;
    bf16* vb_  = kb_ + (size_t)32768 * 1024;
    float* Opart = (float*)kb_;                      // 67MB inside kb+vb (128MB)
    float* ml    = Opart + (size_t)64 * 8 * 256 * 128;

    convert_bf16<<<1024,  256, 0, stream>>>(q, qb_);
    convert_bf16<<<16384, 256, 0, stream>>>(k, kb_);
    convert_bf16<<<16384, 256, 0, stream>>>(v, vb_);
    transpose_w<<<dim3(16, 16), 256, 0, stream>>>(Wq, Wqt);
    transpose_w<<<dim3(16, 16), 256, 0, stream>>>(Wk, Wkt);
    transpose_w<<<dim3(16, 16), 256, 0, stream>>>(Wv, Wvt);
    gemm_bt<false><<<128,  256, 0, stream>>>(qb_, Wqt, bq, qh, 2);
    gemm_bt<false><<<2048, 256, 0, stream>>>(kb_, Wkt, bk, kh, 32);
    gemm_bt<true><<<2048,  256, 0, stream>>>(vb_, Wvt, bv, vt, 32);
    rope_kernel<<<4096,  256, 0, stream>>>(qh, 0);
    rope_kernel<<<65536, 256, 0, stream>>>(kh, 1);
    attn_kernel<<<dim3(64, 8, 4), 256, 0, stream>>>(qh, kh, vt, Opart, ml);
    combine_kernel<<<8192, 256, 0, stream>>>(Opart, ml, out);
}

// Round 5
// 641.011 us; speedup vs baseline: 2.4965x; 1.0945x over previous
//
#include <hip/hip_runtime.h>

typedef __bf16 bf16;
typedef __bf16 bf16x8 __attribute__((ext_vector_type(8)));
typedef float  f32x4  __attribute__((ext_vector_type(4)));

#define MFMA16(a, b, c) __builtin_amdgcn_mfma_f32_16x16x32_bf16((a), (b), (c), 0, 0, 0)

// async global->LDS, 16B per lane; LDS dest = wave-uniform base + lane*16
#define GLOAD_LDS16(gptr, lptr)                                              \
    __builtin_amdgcn_global_load_lds(                                        \
        (const __attribute__((address_space(1))) unsigned int*)(gptr),       \
        (__attribute__((address_space(3))) unsigned int*)(lptr), 16, 0, 0)

constexpr int kDM = 1024;
constexpr int kNTOK = 32768;   // V token count (vt row stride)

static __device__ inline f32x4 zero4() { f32x4 z = {0.f, 0.f, 0.f, 0.f}; return z; }

// ---------------------------------------------------------------------------
// All three W fp32 [k][n] -> Wt bf16 [n][k] transposes in one launch.
// ---------------------------------------------------------------------------
__global__ __launch_bounds__(256) void transpose_all(
    const float* __restrict__ Wq, const float* __restrict__ Wk,
    const float* __restrict__ Wv, bf16* __restrict__ Wqt,
    bf16* __restrict__ Wkt, bf16* __restrict__ Wvt)
{
    __shared__ bf16 T[64][68];
    const float* W = (blockIdx.z == 0) ? Wq : (blockIdx.z == 1) ? Wk : Wv;
    bf16* Wt       = (blockIdx.z == 0) ? Wqt : (blockIdx.z == 1) ? Wkt : Wvt;
    const int tid = threadIdx.x;
    const int n0 = blockIdx.x * 64, k0 = blockIdx.y * 64;
    #pragma unroll
    for (int i = 0; i < 4; i++) {
        const int kk = (tid >> 4) + i * 16, nn4 = (tid & 15) * 4;
        float4 v = *(const float4*)&W[(size_t)(k0 + kk) * kDM + n0 + nn4];
        T[nn4 + 0][kk] = (bf16)v.x; T[nn4 + 1][kk] = (bf16)v.y;
        T[nn4 + 2][kk] = (bf16)v.z; T[nn4 + 3][kk] = (bf16)v.w;
    }
    __syncthreads();
    #pragma unroll
    for (int i = 0; i < 4; i++) {
        const int nn = (tid >> 4) + i * 16, kc = (tid & 15) * 4;
        *(ushort4*)&Wt[(size_t)(n0 + nn) * kDM + k0 + kc] = *(const ushort4*)&T[nn][kc];
    }
}

// ---------------------------------------------------------------------------
// GEMM + fused epilogue: out = X_fp32[M][1024] @ Wt_bf16[N][K]^T + bias
// 128x128 tile, BK=64, 4 waves 2x2. A staged fp32 via global_load_lds
// (32B-granule XOR swizzle, keeps b128 pairs intact, conflict-free frag
// reads), cvt->bf16 on fragment read. B staged bf16 (16B-granule XOR).
// MODE 1: slow RoPE (q) epilogue.  MODE 2: fast RoPE (k) epilogue.
//   RoPE: waves 2,3 (d>=64) deposit x2 into Y; waves 0,1 rotate in fp32;
//   all waves sweep-store vectorized.  n0 block == one head (128 cols).
// MODE 3: no rope, transposed store (V^T, token-contiguous rows).
// ---------------------------------------------------------------------------
template <int MODE>
__global__ __launch_bounds__(256) void gemm_fused(
    const float* __restrict__ X, const bf16* __restrict__ Wt,
    const float* __restrict__ bias, bf16* __restrict__ out, int mtiles_per_xcd)
{
    __shared__ char smem[49152];
    float* Af = (float*)smem;            // [128][64] fp32 staging (32KB)
    bf16*  Bb = (bf16*)(smem + 32768);   // [128][64] bf16 staging (16KB)
    bf16*  Y  = (bf16*)smem;             // [128][136] epilogue buffer (34.8KB)

    const int b    = blockIdx.x;
    const int xcd  = b & 7;
    const int s    = b >> 3;
    const int m0   = (xcd * mtiles_per_xcd + (s >> 3)) * 128;
    const int n0   = (s & 7) * 128;
    const int tid  = threadIdx.x;
    const int wave = tid >> 6;
    const int lane = tid & 63;
    const int quad = lane >> 4, l16 = lane & 15;
    const int mb   = (wave & 1) * 64, nb = (wave >> 1) * 64;

    f32x4 acc[4][4];
    #pragma unroll
    for (int i = 0; i < 4; i++)
        #pragma unroll
        for (int j = 0; j < 4; j++) acc[i][j] = zero4();

    for (int k0 = 0; k0 < kDM; k0 += 64) {
        __syncthreads();
        // A: 32 chunks of 1KB (4 fp32 rows each), 8 per wave.
        // 16B slot s of row goes to LDS slot ((s>>1)^(row&7))*2 + (s&1).
        #pragma unroll
        for (int i = 0; i < 8; i++) {
            const int c = wave * 8 + i;
            const int row = c * 4 + (lane >> 4);
            const int sl  = lane & 15;
            const int src = ((((sl >> 1) ^ (row & 7)) << 1) | (sl & 1)) * 4;
            GLOAD_LDS16(&X[(size_t)(m0 + row) * kDM + k0 + src], &Af[c * 256]);
        }
        // B: 16 chunks of 1KB (8 bf16 rows each), 4 per wave.
        #pragma unroll
        for (int i = 0; i < 4; i++) {
            const int c = wave * 4 + i;
            const int row = c * 8 + (lane >> 3);
            GLOAD_LDS16(&Wt[(size_t)(n0 + row) * kDM + k0 + (((lane & 7) ^ (row & 7)) * 8)],
                        &Bb[c * 512]);
        }
        __syncthreads();
        #pragma unroll
        for (int ks = 0; ks < 2; ks++) {
            bf16x8 a[4], bfr[4];
            #pragma unroll
            for (int i = 0; i < 4; i++) {
                const int m = mb + i * 16 + l16;
                const int G = (ks * 4 + quad) ^ (l16 & 7);   // m&7 == l16&7
                const float* p = &Af[m * 64 + G * 8];
                f32x4 u0 = *(const f32x4*)p;
                f32x4 u1 = *(const f32x4*)(p + 4);
                #pragma unroll
                for (int e = 0; e < 4; e++) { a[i][e] = (bf16)u0[e]; a[i][4 + e] = (bf16)u1[e]; }
            }
            #pragma unroll
            for (int j = 0; j < 4; j++) {
                const int n = nb + j * 16 + l16;
                bfr[j] = *(const bf16x8*)&Bb[n * 64 + (((ks * 4 + quad) ^ (l16 & 7)) * 8)];
            }
            #pragma unroll
            for (int i = 0; i < 4; i++)
                #pragma unroll
                for (int j = 0; j < 4; j++)
                    acc[i][j] = MFMA16(a[i], bfr[j], acc[i][j]);
        }
    }

    __syncthreads();   // staging region about to be reused as Y

    if (MODE == 3) {
        // transposed epilogue: Y[n][m], then vectorized store to out[n][token]
        #pragma unroll
        for (int j = 0; j < 4; j++) {
            const int n = nb + j * 16 + l16;
            const float bv = bias[n0 + n];
            #pragma unroll
            for (int i = 0; i < 4; i++) {
                const int m = mb + i * 16 + quad * 4;
                bf16 tmp[4];
                #pragma unroll
                for (int r = 0; r < 4; r++) tmp[r] = (bf16)(acc[i][j][r] + bv);
                *(ushort4*)&Y[n * 136 + m] = *(const ushort4*)tmp;
            }
        }
        __syncthreads();
        const int row = tid >> 1, seg = (tid & 1) * 64;
        #pragma unroll
        for (int kk = 0; kk < 8; kk++)
            *(uint4*)&out[(size_t)(n0 + row) * kNTOK + m0 + seg + kk * 8] =
                *(const uint4*)&Y[row * 136 + seg + kk * 8];
    } else {
        // RoPE epilogue. phase 1: waves 2,3 deposit x2 (d in [64,128)).
        if (wave >= 2) {
            #pragma unroll
            for (int j = 0; j < 4; j++) {
                const int dcol = 64 + j * 16 + l16;
                const float bv = bias[n0 + dcol];
                #pragma unroll
                for (int i = 0; i < 4; i++)
                    #pragma unroll
                    for (int r = 0; r < 4; r++)
                        Y[(mb + i * 16 + quad * 4 + r) * 136 + dcol] =
                            (bf16)(acc[i][j][r] + bv);
            }
        }
        __syncthreads();
        // phase 2: waves 0,1 rotate (they hold x1, d in [0,64))
        if (wave < 2) {
            #pragma unroll
            for (int j = 0; j < 4; j++) {
                const int d = j * 16 + l16;
                const float bv = bias[n0 + d];
                const float invf = exp2f((float)d * -0.20762050593045951f); // log2(1e4)/64
                #pragma unroll
                for (int i = 0; i < 4; i++) {
                    #pragma unroll
                    for (int r = 0; r < 4; r++) {
                        const int mloc = mb + i * 16 + quad * 4 + r;
                        const int tok = m0 + mloc;
                        int pt, ph, pw;
                        if (MODE == 2) { pt = tok >> 10; ph = (tok >> 5) & 31; pw = tok & 31; }
                        else { int tq = tok >> 8; pt = (31 * tq) / 7;
                               ph = 2 * ((tok >> 4) & 15) + 1; pw = 2 * (tok & 15) + 1; }
                        const int p = (d < 16) ? pt : ((d < 40) ? ph : pw);
                        float sn, cs;
                        __sincosf((float)p * invf, &sn, &cs);
                        const float x1 = acc[i][j][r] + bv;
                        const float x2 = (float)Y[mloc * 136 + 64 + d];
                        Y[mloc * 136 + d]      = (bf16)(x1 * cs - x2 * sn);
                        Y[mloc * 136 + 64 + d] = (bf16)(x2 * cs + x1 * sn);
                    }
                }
            }
        }
        __syncthreads();
        const int row = tid >> 1, seg = (tid & 1) * 64;
        #pragma unroll
        for (int kk = 0; kk < 8; kk++)
            *(uint4*)&out[(size_t)(m0 + row) * kDM + n0 + seg + kk * 8] =
                *(const uint4*)&Y[row * 136 + seg + kk * 8];
    }
}

// ---------------------------------------------------------------------------
// Flash attention, 4-way key split. Grid (z=32, h=8, qb=4) = 1024 blocks =
// exactly 4/CU at 40KB LDS (perfect fill, no tail). l (row-sum of P) via
// MFMA with an all-ones B-fragment built in registers (lane-uniform -> no
// LDS). Ps XOR-swizzled to 8KB unpadded.
// ---------------------------------------------------------------------------
__global__ __launch_bounds__(256) void attn_kernel(
    const bf16* __restrict__ qh, const bf16* __restrict__ kh,
    const bf16* __restrict__ vt, float* __restrict__ Opart, float* __restrict__ ml)
{
    __shared__ bf16 Ks[64 * 128];    // [key][d], 16B-granule swizzle by key&15
    __shared__ bf16 Vs[128 * 64];    // [d][key], 16B-granule swizzle by d&7
    __shared__ bf16 Ps[4][16][64];   // per-wave P, col ^ ((row&7)*8) swizzle

    const int tid  = threadIdx.x;
    const int z    = blockIdx.x, h = blockIdx.y, qb = blockIdx.z;
    const int t    = z >> 2, sp = z & 3;
    const int wave = tid >> 6;
    const int lane = tid & 63;
    const int quad = lane >> 4, l16 = lane & 15;

    const int qrow = qb * 64 + wave * 16 + l16;
    const size_t qbase = ((size_t)(t * 256 + qrow)) * kDM + h * 128;
    bf16x8 aq[4];
    #pragma unroll
    for (int kb = 0; kb < 4; kb++)
        aq[kb] = *(const bf16x8*)&qh[qbase + kb * 32 + quad * 8];

    bf16x8 ones;
    #pragma unroll
    for (int e = 0; e < 8; e++) ones[e] = (bf16)1.0f;

    f32x4 o[9];
    #pragma unroll
    for (int j = 0; j < 9; j++) o[j] = zero4();
    float m_run[4];
    #pragma unroll
    for (int r = 0; r < 4; r++) m_run[r] = -1e30f;
    const float scale = 0.08838834764831845f;   // 1/sqrt(128)

    const int r16 = lane >> 4, j16 = lane & 15;  // K staging coords
    const int r8  = lane >> 3, j8  = lane & 7;   // V staging coords

    for (int kt = 0; kt < 16; kt++) {
        const int kbase = t * 4096 + sp * 1024 + kt * 64;
        __syncthreads();
        #pragma unroll
        for (int i = 0; i < 4; i++) {   // K: 16 chunks (4 key rows each)
            const int c = wave * 4 + i;
            const int krow = c * 4 + r16;
            GLOAD_LDS16(&kh[(size_t)(kbase + krow) * kDM + h * 128 + ((j16 ^ (krow & 15)) * 8)],
                        &Ks[c * 512]);
        }
        #pragma unroll
        for (int i = 0; i < 4; i++) {   // V^T: 16 chunks (8 d rows x 64 keys)
            const int c = wave * 4 + i;
            GLOAD_LDS16(&vt[(size_t)(h * 128 + c * 8 + r8) * kNTOK + kbase + ((j8 ^ r8) * 8)],
                        &Vs[c * 512]);
        }
        __syncthreads();

        // S = Q K^T : 16 q x 64 keys per wave
        f32x4 s[4];
        #pragma unroll
        for (int c = 0; c < 4; c++) s[c] = zero4();
        #pragma unroll
        for (int kb = 0; kb < 4; kb++) {
            #pragma unroll
            for (int c = 0; c < 4; c++) {
                bf16x8 b = *(const bf16x8*)&Ks[(c * 16 + l16) * 128 + (((kb * 4 + quad) ^ l16) * 8)];
                s[c] = MFMA16(aq[kb], b, s[c]);
            }
        }

        // online softmax (max via shfl; sum via ones-frag MFMA)
        float alpha[4];
        #pragma unroll
        for (int r = 0; r < 4; r++) {
            float sv[4];
            #pragma unroll
            for (int c = 0; c < 4; c++) sv[c] = s[c][r] * scale;
            float mx = fmaxf(fmaxf(sv[0], sv[1]), fmaxf(sv[2], sv[3]));
            #pragma unroll
            for (int off = 1; off < 16; off <<= 1) mx = fmaxf(mx, __shfl_xor(mx, off));
            const float mn = fmaxf(m_run[r], mx);
            alpha[r] = __expf(m_run[r] - mn);
            m_run[r] = mn;
            const int q7 = quad * 4 + r;
            #pragma unroll
            for (int c = 0; c < 4; c++) {
                const int col = (c * 16 + l16) ^ ((q7 & 7) * 8);
                Ps[wave][q7][col] = (bf16)__expf(sv[c] - mn);
            }
        }
        #pragma unroll
        for (int j = 0; j < 9; j++)
            #pragma unroll
            for (int r = 0; r < 4; r++) o[j][r] *= alpha[r];
        #pragma unroll
        for (int ks = 0; ks < 2; ks++) {
            bf16x8 pa = *(const bf16x8*)&Ps[wave][l16][((ks * 4 + quad) ^ (l16 & 7)) * 8];
            #pragma unroll
            for (int j = 0; j < 8; j++) {
                bf16x8 bv = *(const bf16x8*)&Vs[(j * 16 + l16) * 64 + (((ks * 4 + quad) ^ (l16 & 7)) * 8)];
                o[j] = MFMA16(pa, bv, o[j]);
            }
            o[8] = MFMA16(pa, ones, o[8]);
        }
    }

    #pragma unroll
    for (int r = 0; r < 4; r++) {
        const int srow = qb * 64 + wave * 16 + quad * 4 + r;
        const size_t pr = ((size_t)(z * 8 + h)) * 256 + srow;
        #pragma unroll
        for (int j = 0; j < 8; j++)
            Opart[pr * 128 + j * 16 + l16] = o[j][r];
        if (l16 == 0) { ml[pr * 2] = m_run[r]; ml[pr * 2 + 1] = o[8][r]; }
    }
}

// ---------------------------------------------------------------------------
// Combine 4 splits: O = sum O_sp*exp(m_sp-m*) / sum l_sp*exp(m_sp-m*)
// ---------------------------------------------------------------------------
__global__ __launch_bounds__(256) void combine_kernel(
    const float* __restrict__ Opart, const float* __restrict__ ml,
    float* __restrict__ out)
{
    const int tid = threadIdx.x;
    const int rid = blockIdx.x * 2 + (tid >> 7);
    const int d   = tid & 127;
    const int t = rid >> 11, h = (rid >> 8) & 7, srow = rid & 255;

    float mv[4], lv[4];
    #pragma unroll
    for (int sp = 0; sp < 4; sp++) {
        const size_t pr = ((size_t)((t * 4 + sp) * 8 + h)) * 256 + srow;
        float2 p = *(const float2*)&ml[pr * 2];
        mv[sp] = p.x; lv[sp] = p.y;
    }
    const float ms = fmaxf(fmaxf(mv[0], mv[1]), fmaxf(mv[2], mv[3]));
    float lsum = 0.f, acc = 0.f;
    #pragma unroll
    for (int sp = 0; sp < 4; sp++) {
        const size_t pr = ((size_t)((t * 4 + sp) * 8 + h)) * 256 + srow;
        const float w = __expf(mv[sp] - ms);
        lsum += lv[sp] * w;
        acc  += Opart[pr * 128 + d] * w;
    }
    out[((size_t)(t * 256 + srow)) * kDM + h * 128 + d] = acc / lsum;
}

// ---------------------------------------------------------------------------
extern "C" void kernel_launch(void* const* d_in, const int* in_sizes, int n_in,
                              void* d_out, int out_size, void* d_ws, size_t ws_size,
                              hipStream_t stream)
{
    const float* q  = (const float*)d_in[0];
    const float* k  = (const float*)d_in[1];
    const float* v  = (const float*)d_in[2];
    const float* Wq = (const float*)d_in[3];
    const float* bq = (const float*)d_in[4];
    const float* Wk = (const float*)d_in[5];
    const float* bk = (const float*)d_in[6];
    const float* Wv = (const float*)d_in[7];
    const float* bv = (const float*)d_in[8];
    float* out = (float*)d_out;

    // ws: qh 4MB | kh 64MB | vt 64MB | Wt x3 6MB | Opart 33.5MB | ml 0.5MB
    bf16* qh  = (bf16*)d_ws;
    bf16* kh  = qh + (size_t)2048 * 1024;
    bf16* vt  = kh + (size_t)32768 * 1024;
    bf16* Wqt = vt + (size_t)32768 * 1024;
    bf16* Wkt = Wqt + (size_t)1024 * 1024;
    bf16* Wvt = Wkt + (size_t)1024 * 1024;
    float* Opart = (float*)(Wvt + (size_t)1024 * 1024);
    float* ml    = Opart + (size_t)32 * 8 * 256 * 128;

    transpose_all<<<dim3(16, 16, 3), 256, 0, stream>>>(Wq, Wk, Wv, Wqt, Wkt, Wvt);
    gemm_fused<1><<<128,  256, 0, stream>>>(q, Wqt, bq, qh, 2);    // q proj + slow rope
    gemm_fused<2><<<2048, 256, 0, stream>>>(k, Wkt, bk, kh, 32);   // k proj + fast rope
    gemm_fused<3><<<2048, 256, 0, stream>>>(v, Wvt, bv, vt, 32);   // v proj, transposed
    attn_kernel<<<dim3(32, 8, 4), 256, 0, stream>>>(qh, kh, vt, Opart, ml);
    combine_kernel<<<8192, 256, 0, stream>>>(Opart, ml, out);
}